// Round 1
// baseline (385.950 us; speedup 1.0000x reference)
//
#include <hip/hip_runtime.h>
#include <hip/hip_bf16.h>

// ScalarQLinear via int8 MFMA, round 6:
//   R5 counters: gemm 127us, MfmaUtil 46%, bank-conflict 0, HBM 28% -> the
//   2-barrier/K-step structure (vmcnt(0) drain each iter) is the bottleneck,
//   not memory. Port the verified 8-phase 256^2 schedule (T3+T4+T5):
//   - 256x256 tile, BK=128, 512 thr, 8 waves (2Mx4N) each 128x64 (acc 8x4).
//   - LDS [buf][kh][256*64B] (K-half OUTER) so staged half-tiles are
//     contiguous -> global_load_lds-compatible; region staged each phase was
//     last read the previous phase (rotation: Bkh0,Akh0 | Bkh1,Akh1).
//   - counted s_waitcnt vmcnt(6) at phases 4/8 only; never 0 in main loop.
//   - s_setprio(1) around each 16-MFMA cluster (pays only with phase split).
//   - chunk swizzle for 64B rows: c4 ^= (row>>1)&3 -> worst 2-way (free).
//   - XCD-chunked block swizzle (512 blocks % 8 == 0, bijective).
//   mfma_i32_16x16x64_i8 lane layouts preserved from R2/R3 (verified).

typedef int int32x4 __attribute__((ext_vector_type(4)));

#define MDIM 8192
#define NDIM 4096
#define KDIM 4096

__device__ __forceinline__ void async_copy16(const void* g, void* l) {
  __builtin_amdgcn_global_load_lds(
      (const __attribute__((address_space(1))) void*)g,
      (__attribute__((address_space(3))) void*)l, 16, 0, 0);
}

__device__ __forceinline__ unsigned pack4(float a, float b, float c, float d) {
  return ((unsigned)((int)a & 0xff)) | ((unsigned)((int)b & 0xff) << 8) |
         ((unsigned)((int)c & 0xff) << 16) | ((unsigned)((int)d & 0xff) << 24);
}

// --- K1: fused quantizers. Blocks [0,4096): w rows; [4096,12288): x rows. ---
__global__ __launch_bounds__(256) void quantize_all(
    const float* __restrict__ w, const float* __restrict__ x,
    unsigned* __restrict__ qw, unsigned* __restrict__ qx,
    float* __restrict__ scale, float* __restrict__ sx) {
  const int t = threadIdx.x;
  __shared__ float wred[4];
  if (blockIdx.x < NDIM) {
    const int row = blockIdx.x;
    const float4* wr = (const float4*)(w + (size_t)row * KDIM);
    float4 v[4];
    float ss = 0.f;
#pragma unroll
    for (int i = 0; i < 4; ++i) {
      v[i] = wr[t + 256 * i];
      ss += v[i].x * v[i].x + v[i].y * v[i].y + v[i].z * v[i].z + v[i].w * v[i].w;
    }
#pragma unroll
    for (int m = 32; m >= 1; m >>= 1) ss += __shfl_xor(ss, m, 64);
    if ((t & 63) == 0) wred[t >> 6] = ss;
    __syncthreads();
    const float safe = fmaxf(sqrtf(wred[0] + wred[1] + wred[2] + wred[3]), 1e-8f);
    unsigned* qr = qw + (size_t)row * (KDIM / 4);
#pragma unroll
    for (int i = 0; i < 4; ++i) {
      float q0 = fminf(fmaxf(rintf(v[i].x / safe * 60.0f), -8.f), 7.f);
      float q1 = fminf(fmaxf(rintf(v[i].y / safe * 60.0f), -8.f), 7.f);
      float q2 = fminf(fmaxf(rintf(v[i].z / safe * 60.0f), -8.f), 7.f);
      float q3 = fminf(fmaxf(rintf(v[i].w / safe * 60.0f), -8.f), 7.f);
      qr[t + 256 * i] = pack4(q0, q1, q2, q3);
    }
    if (t == 0) scale[row] = safe / 60.0f;
  } else {
    const int row = blockIdx.x - NDIM;
    const float4* xr = (const float4*)(x + (size_t)row * KDIM);
    float4 v[4];
    float am = 0.f;
#pragma unroll
    for (int i = 0; i < 4; ++i) {
      v[i] = xr[t + 256 * i];
      am = fmaxf(am, fmaxf(fmaxf(fabsf(v[i].x), fabsf(v[i].y)),
                           fmaxf(fabsf(v[i].z), fabsf(v[i].w))));
    }
#pragma unroll
    for (int m = 32; m >= 1; m >>= 1) am = fmaxf(am, __shfl_xor(am, m, 64));
    if ((t & 63) == 0) wred[t >> 6] = am;
    __syncthreads();
    const float amax =
        fmaxf(fmaxf(fmaxf(wred[0], wred[1]), fmaxf(wred[2], wred[3])), 1e-20f);
    const float r = 127.0f / amax;
    unsigned* qr = qx + (size_t)row * (KDIM / 4);
#pragma unroll
    for (int i = 0; i < 4; ++i) {
      float q0 = fminf(fmaxf(rintf(v[i].x * r), -127.f), 127.f);
      float q1 = fminf(fmaxf(rintf(v[i].y * r), -127.f), 127.f);
      float q2 = fminf(fmaxf(rintf(v[i].z * r), -127.f), 127.f);
      float q3 = fminf(fmaxf(rintf(v[i].w * r), -127.f), 127.f);
      qr[t + 256 * i] = pack4(q0, q1, q2, q3);
    }
    if (t == 0) sx[row] = amax / 127.0f;
  }
}

// --- K2: C[m,n] = sx[m]*scale[n]*dot_i8(A[m,:],B[n,:]) + bias[n] ---
// 8-phase pipelined 256x256 tile, BK=128, 512 threads.

// stage one half-tile (256 rows x 64B, one kh) linearly: 2 loads/thread
#define STAGE(dst, gbase, kt, kh)                                   \
  do {                                                              \
    const char* _g = (gbase) + (kt) * 128 + (kh) * 64;              \
    async_copy16(_g, (dst) + t16);                                  \
    async_copy16(_g + (size_t)128 * KDIM, (dst) + 8192 + t16);      \
  } while (0)

#define LDB(d, h)                                                   \
  _Pragma("unroll") for (int j = 0; j < 4; ++j) bg[j] =             \
      *(const int32x4*)(&sB[d][h][0] + boff + j * 1024);

#define LDA(d, h, mb)                                               \
  _Pragma("unroll") for (int ia = 0; ia < 4; ++ia) af[ia] =         \
      *(const int32x4*)(&sA[d][h][0] + aoff + ((mb) + ia) * 1024);

#define MFMA_BLK(mb)                                                \
  _Pragma("unroll") for (int ic = 0; ic < 4; ++ic)                  \
  _Pragma("unroll") for (int j = 0; j < 4; ++j)                     \
      acc[(mb) + ic][j] = __builtin_amdgcn_mfma_i32_16x16x64_i8(    \
          af[ic], bg[j], acc[(mb) + ic][j], 0, 0, 0);

#define PH_SYNC1()                                                  \
  __builtin_amdgcn_s_barrier();                                     \
  asm volatile("s_waitcnt lgkmcnt(0)" ::: "memory");                \
  __builtin_amdgcn_sched_barrier(0);                                \
  __builtin_amdgcn_s_setprio(1);

#define PH_SYNC2()                                                  \
  __builtin_amdgcn_s_setprio(0);                                    \
  __builtin_amdgcn_sched_barrier(0);                                \
  __builtin_amdgcn_s_barrier();

#define PH_SYNC2V()                                                 \
  __builtin_amdgcn_s_setprio(0);                                    \
  __builtin_amdgcn_sched_barrier(0);                                \
  asm volatile("s_waitcnt vmcnt(6)" ::: "memory");                  \
  __builtin_amdgcn_s_barrier();

__global__ __launch_bounds__(512, 2) void gemm_i8(const char* __restrict__ A,
                                                  const char* __restrict__ B,
                                                  const float* __restrict__ sx,
                                                  const float* __restrict__ scale,
                                                  const float* __restrict__ bias,
                                                  float* __restrict__ C) {
  // [buf][kh][256 rows * 64 B] — kh OUTER so each half-tile is contiguous
  __shared__ __align__(16) char sA[2][2][16384];  // 64 KB
  __shared__ __align__(16) char sB[2][2][16384];  // 64 KB
  const int t = threadIdx.x;
  const int t16 = t * 16;

  // XCD-chunked bijective swizzle: 512 blocks, 8 XCDs, 64/XCD
  const int bid = blockIdx.x;
  const int swz = (bid & 7) * 64 + (bid >> 3);
  const int m0 = (swz >> 4) * 256;  // 32 m-tiles
  const int n0 = (swz & 15) * 256;  // 16 n-tiles

  // staging source: thread t -> (row = t>>2 [+128 on 2nd issue], chunk = t&3)
  // source-swizzled chunk: c4 ^ ((row>>1)&3)  (row bit7 doesn't affect it)
  const int srow = t >> 2;
  const int c4s = (t & 3) ^ ((srow >> 1) & 3);
  const char* gA0 = A + (size_t)(m0 + srow) * KDIM + c4s * 16;
  const char* gB0 = B + (size_t)(n0 + srow) * KDIM + c4s * 16;

  const int lane = t & 63;
  const int wid = t >> 6;
  const int wm = (wid & 1) * 128;   // wave M offset
  const int wn = (wid >> 1) * 64;   // wave N offset
  const int fr = lane & 15;         // A: m, B: n within fragment
  const int q = lane >> 4;          // k-quad (16B chunk within 64B half)
  const int qs = (q ^ ((fr >> 1) & 3)) * 16;  // swizzled chunk byte offset
  const int aoff = (wm + fr) * 64 + qs;
  const int boff = (wn + fr) * 64 + qs;

  int32x4 acc[8][4] = {};
  int32x4 af[4], bg[4];

  // prologue: tile0 fully + tile1 {Bkh0, Akh0, Bkh1} (Akh1 of t1 comes at P0)
  STAGE(&sA[0][0][0], gA0, 0, 0);
  STAGE(&sA[0][1][0], gA0, 0, 1);
  STAGE(&sB[0][0][0], gB0, 0, 0);
  STAGE(&sB[0][1][0], gB0, 0, 1);
  STAGE(&sB[1][0][0], gB0, 1, 0);
  STAGE(&sA[1][0][0], gA0, 1, 0);
  STAGE(&sB[1][1][0], gB0, 1, 1);
  asm volatile("s_waitcnt vmcnt(6)" ::: "memory");  // retire tile0 (8 loads)
  __builtin_amdgcn_s_barrier();

  for (int it = 0; it < 16; ++it) {  // 2 K-tiles / iter, 32 K-tiles total
    const int kt2 = (2 * it + 2) & 31;  // wrap keeps issue rate uniform;
    const int kt3 = (2 * it + 3) & 31;  // wrapped stages are never read
    // P0: buf0 kh0, M-lo  | stage A-kh1(tile 2it+1) -> buf1 (read last P7')
    LDB(0, 0); LDA(0, 0, 0);
    STAGE(&sA[1][1][0], gA0, 2 * it + 1, 1);
    PH_SYNC1(); MFMA_BLK(0); PH_SYNC2();
    // P1: buf0 kh0, M-hi (bg held) | stage B-kh0(kt2) -> buf0 (read last P0)
    LDA(0, 0, 4);
    STAGE(&sB[0][0][0], gB0, kt2, 0);
    PH_SYNC1(); MFMA_BLK(4); PH_SYNC2();
    // P2: buf0 kh1, M-lo | stage A-kh0(kt2) -> buf0 (read last P1)
    LDB(0, 1); LDA(0, 1, 0);
    STAGE(&sA[0][0][0], gA0, kt2, 0);
    PH_SYNC1(); MFMA_BLK(0); PH_SYNC2();
    // P3: buf0 kh1, M-hi | stage B-kh1(kt2) -> buf0 (read last P2) | vmcnt
    LDA(0, 1, 4);
    STAGE(&sB[0][1][0], gB0, kt2, 1);
    PH_SYNC1(); MFMA_BLK(4); PH_SYNC2V();  // retires all of tile 2it+1
    // P4: buf1 kh0, M-lo | stage A-kh1(kt2) -> buf0 (read last P3)
    LDB(1, 0); LDA(1, 0, 0);
    STAGE(&sA[0][1][0], gA0, kt2, 1);
    PH_SYNC1(); MFMA_BLK(0); PH_SYNC2();
    // P5: buf1 kh0, M-hi | stage B-kh0(kt3) -> buf1 (read last P4)
    LDA(1, 0, 4);
    STAGE(&sB[1][0][0], gB0, kt3, 0);
    PH_SYNC1(); MFMA_BLK(4); PH_SYNC2();
    // P6: buf1 kh1, M-lo | stage A-kh0(kt3) -> buf1 (read last P5)
    LDB(1, 1); LDA(1, 1, 0);
    STAGE(&sA[1][0][0], gA0, kt3, 0);
    PH_SYNC1(); MFMA_BLK(0); PH_SYNC2();
    // P7: buf1 kh1, M-hi | stage B-kh1(kt3) -> buf1 (read last P6) | vmcnt
    LDA(1, 1, 4);
    STAGE(&sB[1][1][0], gB0, kt3, 1);
    PH_SYNC1(); MFMA_BLK(4); PH_SYNC2V();  // retires all of tile kt2
  }

  // epilogue: C/D layout col = lane&15, row = quad*4 + reg (verified R2/R3)
  float scl[4], bs[4];
#pragma unroll
  for (int j = 0; j < 4; ++j) {
    const int n = n0 + wn + j * 16 + fr;
    scl[j] = scale[n];
    bs[j] = bias[n];
  }
  const int mrow = q * 4;
#pragma unroll
  for (int im = 0; im < 8; ++im) {
#pragma unroll
    for (int r = 0; r < 4; ++r) {
      const size_t m = (size_t)(m0 + wm + im * 16 + mrow + r);
      const float sxm = sx[m];
      float* crow = C + m * NDIM + (n0 + wn + fr);
#pragma unroll
      for (int j = 0; j < 4; ++j)
        crow[j * 16] = (float)acc[im][j][r] * (sxm * scl[j]) + bs[j];
    }
  }
}

extern "C" void kernel_launch(void* const* d_in, const int* in_sizes, int n_in,
                              void* d_out, int out_size, void* d_ws, size_t ws_size,
                              hipStream_t stream) {
  (void)in_sizes; (void)n_in; (void)out_size; (void)ws_size;
  const float* x = (const float*)d_in[0];     // [8192, 4096] fp32
  const float* w = (const float*)d_in[1];     // [4096, 4096] fp32
  const float* bias = (const float*)d_in[2];  // [4096] fp32
  float* out = (float*)d_out;                 // [8192, 4096] fp32

  char* ws = (char*)d_ws;
  char* qx = ws;                                           // 32 MB int8
  char* qw = ws + (size_t)33554432;                        // 16 MB int8
  float* sx = (float*)(ws + (size_t)50331648);             // 32 KB
  float* scale = (float*)(ws + (size_t)50331648 + 65536);  // 16 KB

  quantize_all<<<NDIM + MDIM, 256, 0, stream>>>(w, x, (unsigned*)qw,
                                                (unsigned*)qx, scale, sx);
  gemm_i8<<<512, 512, 0, stream>>>(qx, qw, sx, scale, bias, out);
}